// Round 3
// baseline (105.338 us; speedup 1.0000x reference)
//
#include <hip/hip_runtime.h>

// Output layout per row (B*N rows, 512 floats each):
//   out[row][i*128 + 2m + 0] = cos(th) + sin(th)
//   out[row][i*128 + 2m + 1] = cos(th) - sin(th)
// with th = 2*pi * x[row][i] * 10000^(-m/64), i in [0,4), m in [0,64).
//
// v_sin_f32 / v_cos_f32 take REVOLUTIONS: sin(2*pi*r). So r = x * 10000^(-m/64)
// directly — no 2*pi multiply, no range reduction (r in [0,1)).
//
// R2: two rows per thread — halves exp/setup/load overhead per byte,
// 8 independent nt dwordx4 stores in flight per thread.

typedef float vf4 __attribute__((ext_vector_type(4)));

__global__ __launch_bounds__(256) void rope_enc_kernel(
    const float* __restrict__ x, float* __restrict__ out, int npairs) {
  int tid  = blockIdx.x * blockDim.x + threadIdx.x;
  int pair = tid >> 5;          // 32 threads per row-pair
  if (pair >= npairs) return;
  int lane = tid & 31;          // owns m = 2*lane, 2*lane+1

  size_t r0 = (size_t)pair * 2;

  vf4 xa = *reinterpret_cast<const vf4*>(x + r0 * 4);
  vf4 xb = *reinterpret_cast<const vf4*>(x + r0 * 4 + 4);
  float xc0[4] = {xa.x, xa.y, xa.z, xa.w};
  float xc1[4] = {xb.x, xb.y, xb.z, xb.w};

  const float C    = 0.20762050593045952f;   // log2(10000)/64
  const float STEP = 0.86596432336006540f;   // 10000^(-1/64)
  float f0 = __builtin_amdgcn_exp2f(-(float)(lane * 2) * C);  // 10000^(-2*lane/64)
  float f1 = f0 * STEP;

  // d = i*128 + 2*m, m = 2*lane  ->  i*128 + 4*lane
  float* orow0 = out + r0 * 512 + (size_t)(lane * 4);
  float* orow1 = orow0 + 512;

#pragma unroll
  for (int i = 0; i < 4; ++i) {
    float ra0 = xc0[i] * f0;
    float ra1 = xc0[i] * f1;
    float rb0 = xc1[i] * f0;
    float rb1 = xc1[i] * f1;
    float sa0 = __builtin_amdgcn_sinf(ra0);
    float ca0 = __builtin_amdgcn_cosf(ra0);
    float sa1 = __builtin_amdgcn_sinf(ra1);
    float ca1 = __builtin_amdgcn_cosf(ra1);
    float sb0 = __builtin_amdgcn_sinf(rb0);
    float cb0 = __builtin_amdgcn_cosf(rb0);
    float sb1 = __builtin_amdgcn_sinf(rb1);
    float cb1 = __builtin_amdgcn_cosf(rb1);
    vf4 va, vb;
    va.x = ca0 + sa0; va.y = ca0 - sa0; va.z = ca1 + sa1; va.w = ca1 - sa1;
    vb.x = cb0 + sb0; vb.y = cb0 - sb0; vb.z = cb1 + sb1; vb.w = cb1 - sb1;
    __builtin_nontemporal_store(va, reinterpret_cast<vf4*>(orow0 + i * 128));
    __builtin_nontemporal_store(vb, reinterpret_cast<vf4*>(orow1 + i * 128));
  }
}

extern "C" void kernel_launch(void* const* d_in, const int* in_sizes, int n_in,
                              void* d_out, int out_size, void* d_ws, size_t ws_size,
                              hipStream_t stream) {
  const float* x = (const float*)d_in[0];
  float* out = (float*)d_out;
  int nrows = in_sizes[0] / 4;              // B*N = 262144
  int npairs = nrows / 2;                   // nrows is even (65536*4)
  int total_threads = npairs * 32;
  dim3 block(256);
  dim3 grid((total_threads + 255) / 256);
  rope_enc_kernel<<<grid, block, 0, stream>>>(x, out, npairs);
}

// Round 4
// 103.815 us; speedup vs baseline: 1.0147x; 1.0147x over previous
//
#include <hip/hip_runtime.h>

// Output layout per row (B*N rows, 512 floats each):
//   out[row][i*128 + 2m + 0] = cos(th) + sin(th)
//   out[row][i*128 + 2m + 1] = cos(th) - sin(th)
// with th = 2*pi * x[row][i] * 10000^(-m/64), i in [0,4), m in [0,64).
//
// v_sin_f32 / v_cos_f32 take REVOLUTIONS — r = x * 10000^(-m/64) directly,
// no 2*pi multiply, no range reduction (r in [0,1)).
//
// R3: persistent grid-stride (2048 blocks), 1 row per 32-thread group per
// iteration (R1 structure), exp hoisted, one-stage x prefetch.

typedef float vf4 __attribute__((ext_vector_type(4)));

__global__ __launch_bounds__(256) void rope_enc_kernel(
    const float* __restrict__ x, float* __restrict__ out, int nrows) {
  int tid   = blockIdx.x * blockDim.x + threadIdx.x;
  int group = tid >> 5;                       // one row per 32-thread group
  int lane  = tid & 31;                       // owns m = 2*lane, 2*lane+1
  int ngroups = (gridDim.x * blockDim.x) >> 5;

  const float C    = 0.20762050593045952f;    // log2(10000)/64
  const float STEP = 0.86596432336006540f;    // 10000^(-1/64)
  float f0 = __builtin_amdgcn_exp2f(-(float)(lane * 2) * C);  // 10000^(-2*lane/64)
  float f1 = f0 * STEP;

  if (group >= nrows) return;

  vf4 xr = *reinterpret_cast<const vf4*>(x + (size_t)group * 4);

  for (int row = group; row < nrows; row += ngroups) {
    int next = row + ngroups;
    vf4 xnext = xr;
    if (next < nrows)
      xnext = *reinterpret_cast<const vf4*>(x + (size_t)next * 4);

    float xc[4] = {xr.x, xr.y, xr.z, xr.w};
    float* orow = out + (size_t)row * 512 + (size_t)(lane * 4);

#pragma unroll
    for (int i = 0; i < 4; ++i) {
      float r0 = xc[i] * f0;
      float r1 = xc[i] * f1;
      float s0 = __builtin_amdgcn_sinf(r0);
      float c0 = __builtin_amdgcn_cosf(r0);
      float s1 = __builtin_amdgcn_sinf(r1);
      float c1 = __builtin_amdgcn_cosf(r1);
      vf4 v;
      v.x = c0 + s0;
      v.y = c0 - s0;
      v.z = c1 + s1;
      v.w = c1 - s1;
      __builtin_nontemporal_store(v, reinterpret_cast<vf4*>(orow + i * 128));
    }
    xr = xnext;
  }
}

extern "C" void kernel_launch(void* const* d_in, const int* in_sizes, int n_in,
                              void* d_out, int out_size, void* d_ws, size_t ws_size,
                              hipStream_t stream) {
  const float* x = (const float*)d_in[0];
  float* out = (float*)d_out;
  int nrows = in_sizes[0] / 4;                // B*N = 262144
  dim3 block(256);
  dim3 grid(2048);                            // persistent: 16384 groups, 16 rows each
  rope_enc_kernel<<<grid, block, 0, stream>>>(x, out, nrows);
}

// Round 5
// 102.319 us; speedup vs baseline: 1.0295x; 1.0146x over previous
//
#include <hip/hip_runtime.h>

// Output layout per row (B*N rows, 512 floats each):
//   out[row][i*128 + 2m + 0] = cos(th) + sin(th)
//   out[row][i*128 + 2m + 1] = cos(th) - sin(th)
// with th = 2*pi * x[row][i] * 10000^(-m/64), i in [0,4), m in [0,64).
//
// v_sin_f32 / v_cos_f32 take REVOLUTIONS — r = x * 10000^(-m/64) directly,
// no 2*pi multiply, no range reduction (r in [0,1)).
//
// R4: R1 structure (one-shot, 1 row per 32-thread group — best so far at
// 95.2 us), single A/B: plain stores instead of nontemporal.

typedef float vf4 __attribute__((ext_vector_type(4)));

__global__ __launch_bounds__(256) void rope_enc_kernel(
    const float* __restrict__ x, float* __restrict__ out, int nrows) {
  int tid  = blockIdx.x * blockDim.x + threadIdx.x;
  int row  = tid >> 5;          // 32 threads per row
  if (row >= nrows) return;
  int lane = tid & 31;          // owns m = 2*lane, 2*lane+1

  vf4 xr = *reinterpret_cast<const vf4*>(x + (size_t)row * 4);
  float xc[4] = {xr.x, xr.y, xr.z, xr.w};

  const float C    = 0.20762050593045952f;   // log2(10000)/64
  const float STEP = 0.86596432336006540f;   // 10000^(-1/64)
  float f0 = __builtin_amdgcn_exp2f(-(float)(lane * 2) * C);  // 10000^(-2*lane/64)
  float f1 = f0 * STEP;

  // d = i*128 + 2*m, m = 2*lane  ->  i*128 + 4*lane
  float* orow = out + (size_t)row * 512 + (size_t)(lane * 4);

#pragma unroll
  for (int i = 0; i < 4; ++i) {
    float r0 = xc[i] * f0;
    float r1 = xc[i] * f1;
    float s0 = __builtin_amdgcn_sinf(r0);
    float c0 = __builtin_amdgcn_cosf(r0);
    float s1 = __builtin_amdgcn_sinf(r1);
    float c1 = __builtin_amdgcn_cosf(r1);
    vf4 v;
    v.x = c0 + s0;
    v.y = c0 - s0;
    v.z = c1 + s1;
    v.w = c1 - s1;
    *reinterpret_cast<vf4*>(orow + i * 128) = v;   // plain store (A/B vs nt)
  }
}

extern "C" void kernel_launch(void* const* d_in, const int* in_sizes, int n_in,
                              void* d_out, int out_size, void* d_ws, size_t ws_size,
                              hipStream_t stream) {
  const float* x = (const float*)d_in[0];
  float* out = (float*)d_out;
  int nrows = in_sizes[0] / 4;              // B*N = 262144
  int total_threads = nrows * 32;
  dim3 block(256);
  dim3 grid((total_threads + 255) / 256);
  rope_enc_kernel<<<grid, block, 0, stream>>>(x, out, nrows);
}

// Round 6
// 95.171 us; speedup vs baseline: 1.1068x; 1.0751x over previous
//
#include <hip/hip_runtime.h>

// Output layout per row (B*N rows, 512 floats each):
//   out[row][i*128 + 2k + 0] = cos(th) + sin(th)
//   out[row][i*128 + 2k + 1] = cos(th) - sin(th)
// with th = 2*pi * x[row][i] * 10000^(-k/64), i in [0,4), k in [0,64).
//
// v_sin_f32 / v_cos_f32 take REVOLUTIONS — r = x * 10000^(-k/64) directly,
// no 2*pi multiply, no range reduction (r in [0,1)).
//
// R5: same compute/grid/nt as R1 (best, 95.2us). Single variable: each
// 64-lane wave owns a row PAIR and every store instruction is one
// contiguous 1KB span (vs R1's two 512B segments 2KB apart).
//   iteration t: row = 2w + (t>>1), float offset p = (t&1)*256 + lane*4
//   -> coord i = (t&1)*2 + (lane>>5), freq pair k0 = 2*(lane&31).

typedef float vf4 __attribute__((ext_vector_type(4)));

__global__ __launch_bounds__(256) void rope_enc_kernel(
    const float* __restrict__ x, float* __restrict__ out, int npairs) {
  int tid  = blockIdx.x * blockDim.x + threadIdx.x;
  int wave = tid >> 6;            // one row-pair per 64-lane wave
  if (wave >= npairs) return;
  int l  = tid & 63;
  int hi = l >> 5;                // 0: lanes 0-31, 1: lanes 32-63
  int lk = l & 31;                // freq pair k0 = 2*lk

  size_t r0 = (size_t)wave * 2;
  vf4 xa = *reinterpret_cast<const vf4*>(x + r0 * 4);      // row 2w
  vf4 xb = *reinterpret_cast<const vf4*>(x + r0 * 4 + 4);  // row 2w+1

  const float C    = 0.20762050593045952f;   // log2(10000)/64
  const float STEP = 0.86596432336006540f;   // 10000^(-1/64)
  float f0 = __builtin_amdgcn_exp2f(-(float)(lk * 2) * C); // 10000^(-2*lk/64)
  float f1 = f0 * STEP;

  float* obase = out + r0 * 512 + (size_t)(l * 4);

#pragma unroll
  for (int t = 0; t < 4; ++t) {
    vf4 xr = (t < 2) ? xa : xb;                       // compile-time select
    float cv = ((t & 1) == 0) ? (hi ? xr.y : xr.x)    // coord i = (t&1)*2 + hi
                              : (hi ? xr.w : xr.z);
    float p0 = cv * f0;
    float p1 = cv * f1;
    float s0 = __builtin_amdgcn_sinf(p0);
    float c0 = __builtin_amdgcn_cosf(p0);
    float s1 = __builtin_amdgcn_sinf(p1);
    float c1 = __builtin_amdgcn_cosf(p1);
    vf4 v;
    v.x = c0 + s0;
    v.y = c0 - s0;
    v.z = c1 + s1;
    v.w = c1 - s1;
    float* addr = obase + (size_t)((t >> 1) * 512 + (t & 1) * 256);
    __builtin_nontemporal_store(v, reinterpret_cast<vf4*>(addr));
  }
}

extern "C" void kernel_launch(void* const* d_in, const int* in_sizes, int n_in,
                              void* d_out, int out_size, void* d_ws, size_t ws_size,
                              hipStream_t stream) {
  const float* x = (const float*)d_in[0];
  float* out = (float*)d_out;
  int nrows = in_sizes[0] / 4;              // B*N = 262144
  int npairs = nrows / 2;                   // even (4*65536)
  int total_threads = npairs * 64;
  dim3 block(256);
  dim3 grid((total_threads + 255) / 256);
  rope_enc_kernel<<<grid, block, 0, stream>>>(x, out, npairs);
}